// Round 1
// baseline (12265.891 us; speedup 1.0000x reference)
//
#include <hip/hip_runtime.h>
#include <cmath>

#define B_ 64
#define S_ 1024
#define I_ 512
#define H_ 1024
#define O_ 512
#define HB (H_ * B_)   // 65536

// ---------------------------------------------------------------------------
// Input projection: xp[s][h][b] = sum_i x[b][s][i] * Wih[h][i] + bih[h] + bhh[h]
// GEMM per s: M=h(1024, 16 tiles), N=b(64), K=i(512). Tile 64x64, 4x4/thread.
// ---------------------------------------------------------------------------
__global__ __launch_bounds__(256) void k_inproj(const float* __restrict__ x,
                                                const float* __restrict__ Wih,
                                                const float* __restrict__ bih,
                                                const float* __restrict__ bhh,
                                                float* __restrict__ xp) {
  __shared__ float As[64][36];   // W_ih tile, row-major (m=h, k contiguous), pad->2-way free
  __shared__ float Bs[32][72];   // x tile, k-major: Bs[k][b], pad 72 -> aligned + 2-way free
  const int s  = blockIdx.y;
  const int h0 = blockIdx.x * 64;
  const int t  = threadIdx.x;
  const int tx = t & 15, ty = t >> 4;
  float acc[4][4] = {};
  for (int k0 = 0; k0 < I_; k0 += 32) {
    #pragma unroll
    for (int L = 0; L < 2; L++) {
      int f = L * 256 + t;
      int row = f >> 3, c4 = (f & 7) * 4;
      float4 v = *(const float4*)&Wih[(size_t)(h0 + row) * I_ + k0 + c4];
      *(float4*)&As[row][c4] = v;
    }
    #pragma unroll
    for (int L = 0; L < 2; L++) {
      int f = L * 256 + t;
      int row = f >> 3, c4 = (f & 7) * 4;   // row = b
      float4 v = *(const float4*)&x[(size_t)row * (S_ * I_) + (size_t)s * I_ + k0 + c4];
      Bs[c4 + 0][row] = v.x;
      Bs[c4 + 1][row] = v.y;
      Bs[c4 + 2][row] = v.z;
      Bs[c4 + 3][row] = v.w;
    }
    __syncthreads();
    #pragma unroll
    for (int k = 0; k < 32; k += 4) {
      float4 a[4], b[4];
      #pragma unroll
      for (int r = 0; r < 4; r++) a[r] = *(const float4*)&As[ty * 4 + r][k];
      #pragma unroll
      for (int kk = 0; kk < 4; kk++) b[kk] = *(const float4*)&Bs[k + kk][tx * 4];
      #pragma unroll
      for (int kk = 0; kk < 4; kk++)
        #pragma unroll
        for (int r = 0; r < 4; r++)
          #pragma unroll
          for (int c = 0; c < 4; c++)
            acc[r][c] += ((const float*)&a[r])[kk] * ((const float*)&b[kk])[c];
    }
    __syncthreads();
  }
  #pragma unroll
  for (int r = 0; r < 4; r++) {
    int h = h0 + ty * 4 + r;
    float bias = bih[h] + bhh[h];
    float4 o;
    o.x = acc[r][0] + bias;
    o.y = acc[r][1] + bias;
    o.z = acc[r][2] + bias;
    o.w = acc[r][3] + bias;
    *(float4*)&xp[(size_t)s * HB + (size_t)h * 64 + tx * 4] = o;
  }
}

// ---------------------------------------------------------------------------
// One recurrence step: hsl[j][b] = tanh(hsl[j][b](=xp) + sum_k hprev[k][b]*Whh[j][k])
// hprev, hsl are (H,B) slices. 256 blocks: 4 j-rows each; 4 waves split K;
// W reads are wave-uniform -> scalar loads; h reads lane-coalesced (lane=b).
// ---------------------------------------------------------------------------
__global__ __launch_bounds__(256) void k_step(const float* __restrict__ hprev,
                                              const float* __restrict__ Whh,
                                              float* __restrict__ hsl) {
  __shared__ float red[4][4][64];
  const int t = threadIdx.x;
  const int b = t & 63;
  const int w = __builtin_amdgcn_readfirstlane(t >> 6);  // force SGPR
  const int j0 = blockIdx.x * 4;
  const int kb = w * 256;
  const float* __restrict__ hp  = hprev + (size_t)kb * 64 + b;
  const float* __restrict__ wr0 = Whh + (size_t)(j0 + 0) * H_ + kb;
  const float* __restrict__ wr1 = Whh + (size_t)(j0 + 1) * H_ + kb;
  const float* __restrict__ wr2 = Whh + (size_t)(j0 + 2) * H_ + kb;
  const float* __restrict__ wr3 = Whh + (size_t)(j0 + 3) * H_ + kb;
  float p0 = 0.f, p1 = 0.f, p2 = 0.f, p3 = 0.f;
  for (int k = 0; k < 256; k += 4) {
    const float4 w0 = *(const float4*)(wr0 + k);
    const float4 w1 = *(const float4*)(wr1 + k);
    const float4 w2 = *(const float4*)(wr2 + k);
    const float4 w3 = *(const float4*)(wr3 + k);
    const float hv0 = hp[(k + 0) * 64];
    const float hv1 = hp[(k + 1) * 64];
    const float hv2 = hp[(k + 2) * 64];
    const float hv3 = hp[(k + 3) * 64];
    p0 += hv0 * w0.x + hv1 * w0.y + hv2 * w0.z + hv3 * w0.w;
    p1 += hv0 * w1.x + hv1 * w1.y + hv2 * w1.z + hv3 * w1.w;
    p2 += hv0 * w2.x + hv1 * w2.y + hv2 * w2.z + hv3 * w2.w;
    p3 += hv0 * w3.x + hv1 * w3.y + hv2 * w3.z + hv3 * w3.w;
  }
  red[w][0][b] = p0;
  red[w][1][b] = p1;
  red[w][2][b] = p2;
  red[w][3][b] = p3;
  __syncthreads();
  const int j = t >> 6;
  float sum = red[0][j][b] + red[1][j][b] + red[2][j][b] + red[3][j][b];
  const size_t oi = (size_t)(j0 + j) * 64 + b;
  hsl[oi] = tanhf(hsl[oi] + sum);
}

// ---------------------------------------------------------------------------
// Output projection: out[b][s][o] = sum_h hs[s][h][b] * Who[o][h] + bho[o]
// GEMM per s: M=b(64), N=o(512, 8 tiles), K=h(1024). Tile 64x64, 4x4/thread.
// ---------------------------------------------------------------------------
__global__ __launch_bounds__(256) void k_outproj(const float* __restrict__ hs,
                                                 const float* __restrict__ Who,
                                                 const float* __restrict__ bho,
                                                 float* __restrict__ out) {
  __shared__ float As[32][72];  // hs tile, k-major: As[k][b] (native layout)
  __shared__ float Bs[32][72];  // Who tile, k-major: Bs[k][o]
  const int s  = blockIdx.y;
  const int o0 = blockIdx.x * 64;
  const int t  = threadIdx.x;
  const int tx = t & 15, ty = t >> 4;
  const float* __restrict__ hsS = hs + (size_t)s * HB;
  float acc[4][4] = {};
  for (int k0 = 0; k0 < H_; k0 += 32) {
    #pragma unroll
    for (int L = 0; L < 2; L++) {
      int f = L * 256 + t;
      int kk = f >> 4, b4 = (f & 15) * 4;
      *(float4*)&As[kk][b4] = *(const float4*)&hsS[(size_t)(k0 + kk) * 64 + b4];
    }
    #pragma unroll
    for (int L = 0; L < 2; L++) {
      int f = L * 256 + t;
      int row = f >> 3, c4 = (f & 7) * 4;   // row = o
      float4 v = *(const float4*)&Who[(size_t)(o0 + row) * H_ + k0 + c4];
      Bs[c4 + 0][row] = v.x;
      Bs[c4 + 1][row] = v.y;
      Bs[c4 + 2][row] = v.z;
      Bs[c4 + 3][row] = v.w;
    }
    __syncthreads();
    #pragma unroll
    for (int k = 0; k < 32; k += 4) {
      float4 a4[4], b4[4];
      #pragma unroll
      for (int kk = 0; kk < 4; kk++) a4[kk] = *(const float4*)&As[k + kk][ty * 4];
      #pragma unroll
      for (int kk = 0; kk < 4; kk++) b4[kk] = *(const float4*)&Bs[k + kk][tx * 4];
      #pragma unroll
      for (int kk = 0; kk < 4; kk++)
        #pragma unroll
        for (int r = 0; r < 4; r++)
          #pragma unroll
          for (int c = 0; c < 4; c++)
            acc[r][c] += ((const float*)&a4[kk])[r] * ((const float*)&b4[kk])[c];
    }
    __syncthreads();
  }
  #pragma unroll
  for (int r = 0; r < 4; r++) {
    int b = ty * 4 + r;
    float4 o4;
    o4.x = acc[r][0] + bho[o0 + tx * 4 + 0];
    o4.y = acc[r][1] + bho[o0 + tx * 4 + 1];
    o4.z = acc[r][2] + bho[o0 + tx * 4 + 2];
    o4.w = acc[r][3] + bho[o0 + tx * 4 + 3];
    *(float4*)&out[(size_t)b * (S_ * O_) + (size_t)s * O_ + o0 + tx * 4] = o4;
  }
}

// (B,H) -> (H,B)
__global__ void k_transpose_bh_to_hb(const float* __restrict__ src, float* __restrict__ dst) {
  int idx = blockIdx.x * 256 + threadIdx.x;  // 65536 total
  int h = idx >> 6, b = idx & 63;
  dst[h * 64 + b] = src[b * H_ + h];
}

// last hidden: (H,B) slice -> out (B,H)
__global__ void k_lasth(const float* __restrict__ hlast, float* __restrict__ out) {
  int idx = blockIdx.x * 256 + threadIdx.x;  // 65536 total
  int b = idx >> 10, h = idx & 1023;
  out[idx] = hlast[h * 64 + b];
}

extern "C" void kernel_launch(void* const* d_in, const int* in_sizes, int n_in,
                              void* d_out, int out_size, void* d_ws, size_t ws_size,
                              hipStream_t stream) {
  const float* x    = (const float*)d_in[0];
  const float* h0   = (const float*)d_in[1];
  const float* Wih  = (const float*)d_in[2];
  const float* bih  = (const float*)d_in[3];
  const float* Whh  = (const float*)d_in[4];
  const float* bhh  = (const float*)d_in[5];
  const float* Who  = (const float*)d_in[6];
  const float* bho  = (const float*)d_in[7];
  float* out = (float*)d_out;

  // ws layout: xp/hs buffer (S,H,B) fp32 = 268.4 MB, then hT0 (H,B) = 256 KB
  float* xp  = (float*)d_ws;
  float* hT0 = xp + (size_t)S_ * HB;

  k_transpose_bh_to_hb<<<256, 256, 0, stream>>>(h0, hT0);
  k_inproj<<<dim3(16, S_), 256, 0, stream>>>(x, Wih, bih, bhh, xp);
  for (int s = 0; s < S_; s++) {
    const float* hp = (s == 0) ? hT0 : xp + (size_t)(s - 1) * HB;
    k_step<<<256, 256, 0, stream>>>(hp, Whh, xp + (size_t)s * HB);
  }
  k_outproj<<<dim3(8, S_), 256, 0, stream>>>(xp, Who, bho, out);
  k_lasth<<<256, 256, 0, stream>>>(xp + (size_t)(S_ - 1) * HB, out + (size_t)B_ * S_ * O_);
}